// Round 4
// baseline (1264.639 us; speedup 1.0000x reference)
//
#include <hip/hip_runtime.h>

#define S 2048
#define DD 64
#define NH 32           // B*H
#define NW 8            // waves per block
#define KSLICE 256      // k columns per wave
#define NT 16           // 16-wide k tiles per wave

typedef float f32x4 __attribute__((ext_vector_type(4)));
typedef unsigned int u32x4 __attribute__((ext_vector_type(4)));
typedef short bf16x8 __attribute__((ext_vector_type(8)));

__device__ inline unsigned int packsplit(float x){
  unsigned int u = __float_as_uint(x);
  unsigned int h = u >> 16;
  float rem = x - __uint_as_float(h << 16);
  unsigned int l = __float_as_uint(rem) >> 16;
  return (h << 16) | l;
}
__device__ inline void split2(float x, short &hi, short &lo){
  unsigned int p = packsplit(x);
  hi = (short)(p >> 16); lo = (short)(p & 0xFFFFu);
}
__device__ inline f32x4 ntload4(const float* p){
  return __builtin_nontemporal_load(reinterpret_cast<const f32x4*>(p));
}
__device__ inline void ntstore4(float* p, f32x4 v){
  __builtin_nontemporal_store(v, reinterpret_cast<f32x4*>(p));
}

// ---- pre-pack kernels ----
__global__ void pack_k_kernel(const float* __restrict__ in, unsigned int* __restrict__ out, int n4){
  int i = blockIdx.x * 256 + threadIdx.x;
  if (i < n4){
    f32x4 x = ntload4(in + 4*(size_t)i);
    u32x4 p;
    p.x = packsplit(x.x); p.y = packsplit(x.y);
    p.z = packsplit(x.z); p.w = packsplit(x.w);
    reinterpret_cast<u32x4*>(out)[i] = p;
  }
}

__global__ void pack_vt_kernel(const float* __restrict__ v, unsigned int* __restrict__ vt){
  const int head = blockIdx.x >> 5;
  const int s0   = (blockIdx.x & 31) * 64;
  const float* vh = v + (size_t)head * S * DD;
  unsigned int* vth = vt + (size_t)head * DD * S;
  __shared__ unsigned int tile[64][65];
  const int tid = threadIdx.x;
  for (int i = tid; i < 64*64; i += 256){
    int s = i >> 6, d = i & 63;
    tile[d][s] = packsplit(__builtin_nontemporal_load(&vh[(size_t)(s0 + s) * DD + d]));
  }
  __syncthreads();
  for (int i = tid; i < 64*64; i += 256){
    int d = i >> 6, s = i & 63;
    vth[(size_t)d * S + s0 + s] = tile[d][s];
  }
}

// ---- fused attention ----
template<bool PACKED>
__global__ __launch_bounds__(512, 2)
void attn_fused_kernel(const float* __restrict__ q, const float* __restrict__ k,
                       const float* __restrict__ v, const float* __restrict__ bias,
                       const float* __restrict__ gb,
                       const unsigned int* __restrict__ kp,
                       const unsigned int* __restrict__ vtp,
                       float* __restrict__ out, float* __restrict__ wout)
{
  const int head = blockIdx.y;
  const int q0   = blockIdx.x * 16;
  const int tid  = threadIdx.x;
  const int wid  = tid >> 6;
  const int lane = tid & 63;
  const int lr   = lane & 15;
  const int lg   = lane >> 4;

  const float* qh = q    + (size_t)head * S * DD;
  const float* kh = k    + (size_t)head * S * DD;
  const float* vh = v    + (size_t)head * S * DD;
  const float* bh = bias + (size_t)head * S * S;
  const float* gh = gb   + (size_t)head * S * S;
  const unsigned int* kph  = kp  + (size_t)head * S * DD;
  const unsigned int* vtph = vtp + (size_t)head * DD * S;
  float* oh = out  + (size_t)head * S * DD;
  float* wh = wout + (size_t)head * S * S;

  __shared__ unsigned int sW[NW][16][68];
  __shared__ float redm[NW][16];
  __shared__ float redl[NW][16];

  // ---- Q fragments (B operand: lane holds Q[q0+lr][32ks + lg*8+j]), pre-scaled
  bf16x8 qhi[2], qlo[2];
  {
    const float* qrow = qh + (size_t)(q0 + lr) * DD;
#pragma unroll
    for (int ks = 0; ks < 2; ++ks){
      float4 a = *reinterpret_cast<const float4*>(qrow + ks*32 + lg*8);
      float4 b = *reinterpret_cast<const float4*>(qrow + ks*32 + lg*8 + 4);
      float f[8] = {a.x,a.y,a.z,a.w,b.x,b.y,b.z,b.w};
#pragma unroll
      for (int j = 0; j < 8; ++j){
        short h, l2; split2(f[j] * 0.125f, h, l2);
        qhi[ks][j] = h; qlo[ks][j] = l2;
      }
    }
  }

  const int kw0 = wid * KSLICE;
  f32x4 acc[NT];
#pragma unroll
  for (int t = 0; t < NT; ++t) acc[t] = (f32x4){0.f,0.f,0.f,0.f};

  // ---- Phase 1a: pure QK^T (K is L2-resident; homogeneous short-latency loop)
#pragma unroll 2
  for (int t = 0; t < NT; ++t){
    const int kbase = kw0 + 16*t;
    bf16x8 khi[2], klo[2];
    if constexpr (PACKED){
      const unsigned int* kr = kph + (size_t)(kbase + lr) * DD;
#pragma unroll
      for (int ks = 0; ks < 2; ++ks){
        uint4 p0 = *reinterpret_cast<const uint4*>(kr + ks*32 + lg*8);
        uint4 p1 = *reinterpret_cast<const uint4*>(kr + ks*32 + lg*8 + 4);
        unsigned int pw[8] = {p0.x,p0.y,p0.z,p0.w,p1.x,p1.y,p1.z,p1.w};
#pragma unroll
        for (int j = 0; j < 8; ++j){
          khi[ks][j] = (short)(pw[j] >> 16);
          klo[ks][j] = (short)(pw[j] & 0xFFFFu);
        }
      }
    } else {
      const float* krow = kh + (size_t)(kbase + lr) * DD;
#pragma unroll
      for (int ks = 0; ks < 2; ++ks){
        float4 a = *reinterpret_cast<const float4*>(krow + ks*32 + lg*8);
        float4 b = *reinterpret_cast<const float4*>(krow + ks*32 + lg*8 + 4);
        float f[8] = {a.x,a.y,a.z,a.w,b.x,b.y,b.z,b.w};
#pragma unroll
        for (int j = 0; j < 8; ++j){
          short h, l2; split2(f[j], h, l2);
          khi[ks][j] = h; klo[ks][j] = l2;
        }
      }
    }
#pragma unroll
    for (int ks = 0; ks < 2; ++ks){
      acc[t] = __builtin_amdgcn_mfma_f32_16x16x32_bf16(klo[ks], qhi[ks], acc[t], 0,0,0);
      acc[t] = __builtin_amdgcn_mfma_f32_16x16x32_bf16(khi[ks], qlo[ks], acc[t], 0,0,0);
      acc[t] = __builtin_amdgcn_mfma_f32_16x16x32_bf16(khi[ks], qhi[ks], acc[t], 0,0,0);
    }
  }

  // ---- Phase 1b: bias + gaussian penalty — pure HBM streaming loop,
  //      independent iterations; freed VGPRs let the compiler pipeline deep.
  {
    const float* brow = bh + (size_t)(q0 + lr) * S + kw0 + lg*4;
    const float* grow = gh + (size_t)(q0 + lr) * S + kw0 + lg*4;
#pragma unroll
    for (int t = 0; t < NT; ++t){
      f32x4 b4 = ntload4(brow + 16*t);
      f32x4 g4 = ntload4(grow + 16*t);
#pragma unroll
      for (int r = 0; r < 4; ++r)
        acc[t][r] += b4[r] - 0.5f * g4[r] * g4[r];
    }
  }

  // ---- Phase 2: softmax. Row q0+lr fully owned along (lg, r, t, wave).
  float mrow;
  {
    float mm = -3.4e38f;
#pragma unroll
    for (int t = 0; t < NT; ++t)
#pragma unroll
      for (int r = 0; r < 4; ++r) mm = fmaxf(mm, acc[t][r]);
    mm = fmaxf(mm, __shfl_xor(mm, 16, 64));
    mm = fmaxf(mm, __shfl_xor(mm, 32, 64));
    if (lane < 16) redm[wid][lane] = mm;
  }
  __syncthreads();
  {
    float mm = redm[0][lr];
#pragma unroll
    for (int w = 1; w < NW; ++w) mm = fmaxf(mm, redm[w][lr]);
    mrow = mm;
  }

  float inv;
  {
    float s = 0.f;
#pragma unroll
    for (int t = 0; t < NT; ++t)
#pragma unroll
      for (int r = 0; r < 4; ++r){
        float e = __expf(acc[t][r] - mrow);
        acc[t][r] = e;
        s += e;
      }
    s += __shfl_xor(s, 16, 64);
    s += __shfl_xor(s, 32, 64);
    if (lane < 16) redl[wid][lane] = s;
    __syncthreads();
    float tot = 0.f;
#pragma unroll
    for (int w = 0; w < NW; ++w) tot += redl[w][lr];
    inv = 1.0f / tot;
  }

  // ---- Phase 3+4: normalize+pack to LDS, full-line nt weight stores, PV
  f32x4 oacc[4];
#pragma unroll
  for (int n = 0; n < 4; ++n) oacc[n] = (f32x4){0.f,0.f,0.f,0.f};

  const int rg8 = lane >> 3;   // 0..7
  const int jj8 = lane & 7;    // 0..7

#pragma unroll 1
  for (int c = 0; c < 4; ++c){
#pragma unroll
    for (int tt = 0; tt < 4; ++tt){
      const int t = 4*c + tt;
      u32x4 pw;
#pragma unroll
      for (int r = 0; r < 4; ++r)
        pw[r] = packsplit(acc[t][r] * inv);
      *reinterpret_cast<u32x4*>(&sW[wid][lr][16*tt + lg*4]) = pw;
    }
    // wave-private weight write-out: 8 rows x 128B full-line segments per instr
#pragma unroll
    for (int p = 0; p < 2; ++p){
      const int row = p*8 + rg8;
#pragma unroll
      for (int h = 0; h < 2; ++h){
        u32x4 pk = *reinterpret_cast<const u32x4*>(&sW[wid][row][h*32 + jj8*4]);
        f32x4 wv;
#pragma unroll
        for (int e = 0; e < 4; ++e)
          wv[e] = __uint_as_float(pk[e] & 0xFFFF0000u) + __uint_as_float(pk[e] << 16);
        ntstore4(wh + (size_t)(q0 + row) * S + kw0 + 64*c + h*32 + jj8*4, wv);
      }
    }
    const int kc = kw0 + 64*c;
#pragma unroll
    for (int ks = 0; ks < 2; ++ks){
      uint4 pa0 = *reinterpret_cast<const uint4*>(&sW[wid][lr][32*ks + lg*8]);
      uint4 pa1 = *reinterpret_cast<const uint4*>(&sW[wid][lr][32*ks + lg*8 + 4]);
      unsigned int pa[8] = {pa0.x,pa0.y,pa0.z,pa0.w,pa1.x,pa1.y,pa1.z,pa1.w};
      bf16x8 ahi, alo;
#pragma unroll
      for (int j = 0; j < 8; ++j){
        ahi[j] = (short)(pa[j] >> 16);
        alo[j] = (short)(pa[j] & 0xFFFFu);
      }
#pragma unroll
      for (int n = 0; n < 4; ++n){
        bf16x8 bhi, blo;
        if constexpr (PACKED){
          const unsigned int* vrow = vtph + (size_t)(16*n + lr) * S + kc + 32*ks + lg*8;
          uint4 p0 = *reinterpret_cast<const uint4*>(vrow);
          uint4 p1 = *reinterpret_cast<const uint4*>(vrow + 4);
          unsigned int pw[8] = {p0.x,p0.y,p0.z,p0.w,p1.x,p1.y,p1.z,p1.w};
#pragma unroll
          for (int j = 0; j < 8; ++j){
            bhi[j] = (short)(pw[j] >> 16);
            blo[j] = (short)(pw[j] & 0xFFFFu);
          }
        } else {
#pragma unroll
          for (int j = 0; j < 8; ++j){
            float x = vh[(size_t)(kc + 32*ks + lg*8 + j) * DD + 16*n + lr];
            short h, l2; split2(x, h, l2);
            bhi[j] = h; blo[j] = l2;
          }
        }
        oacc[n] = __builtin_amdgcn_mfma_f32_16x16x32_bf16(alo, bhi, oacc[n], 0,0,0);
        oacc[n] = __builtin_amdgcn_mfma_f32_16x16x32_bf16(ahi, blo, oacc[n], 0,0,0);
        oacc[n] = __builtin_amdgcn_mfma_f32_16x16x32_bf16(ahi, bhi, oacc[n], 0,0,0);
      }
    }
  }

  // ---- Phase 5: cross-wave reduction of out partials (alias sW)
  float (*sO)[16][68] = reinterpret_cast<float(*)[16][68]>(sW);
  __syncthreads();
#pragma unroll
  for (int n = 0; n < 4; ++n)
#pragma unroll
    for (int r = 0; r < 4; ++r)
      sO[wid][lg*4 + r][16*n + lr] = oacc[n][r];
  __syncthreads();
#pragma unroll
  for (int i = tid; i < 16*64; i += 512){
    int row = i >> 6, d = i & 63;
    float s = 0.f;
#pragma unroll
    for (int w = 0; w < NW; ++w) s += sO[w][row][d];
    __builtin_nontemporal_store(s, &oh[(size_t)(q0 + row) * DD + d]);
  }
}

extern "C" void kernel_launch(void* const* d_in, const int* in_sizes, int n_in,
                              void* d_out, int out_size, void* d_ws, size_t ws_size,
                              hipStream_t stream) {
  const float* q    = (const float*)d_in[0];
  const float* k    = (const float*)d_in[1];
  const float* v    = (const float*)d_in[2];
  const float* bias = (const float*)d_in[3];
  const float* gb   = (const float*)d_in[4];
  float* out  = (float*)d_out;
  float* wout = (float*)d_out + (size_t)NH * S * DD;

  const size_t nelem = (size_t)NH * S * DD;       // 4.19M
  const size_t need  = 2 * nelem * sizeof(unsigned int);

  dim3 grid(S / 16, NH);
  dim3 block(512);

  if (ws_size >= need){
    unsigned int* kp  = (unsigned int*)d_ws;
    unsigned int* vtp = kp + nelem;
    int n4 = (int)(nelem / 4);
    pack_k_kernel<<<(n4 + 255) / 256, 256, 0, stream>>>(k, kp, n4);
    pack_vt_kernel<<<NH * 32, 256, 0, stream>>>(v, vtp);
    attn_fused_kernel<true><<<grid, block, 0, stream>>>(q, k, v, bias, gb, kp, vtp, out, wout);
  } else {
    attn_fused_kernel<false><<<grid, block, 0, stream>>>(q, k, v, bias, gb, nullptr, nullptr, out, wout);
  }
}

// Round 5
// 1238.012 us; speedup vs baseline: 1.0215x; 1.0215x over previous
//
#include <hip/hip_runtime.h>

#define S 2048
#define DD 64
#define NH 32           // B*H
#define NW 8            // waves per block
#define KSLICE 256      // k columns per wave
#define NT 16           // 16-wide k tiles per wave

typedef float f32x4 __attribute__((ext_vector_type(4)));
typedef unsigned int u32x4 __attribute__((ext_vector_type(4)));
typedef short bf16x8 __attribute__((ext_vector_type(8)));

__device__ inline unsigned int packsplit(float x){
  unsigned int u = __float_as_uint(x);
  unsigned int h = u >> 16;
  float rem = x - __uint_as_float(h << 16);
  unsigned int l = __float_as_uint(rem) >> 16;
  return (h << 16) | l;
}
__device__ inline void split2(float x, short &hi, short &lo){
  unsigned int p = packsplit(x);
  hi = (short)(p >> 16); lo = (short)(p & 0xFFFFu);
}
__device__ inline f32x4 ntload4(const float* p){
  return __builtin_nontemporal_load(reinterpret_cast<const f32x4*>(p));
}
__device__ inline void ntstore4(float* p, f32x4 v){
  __builtin_nontemporal_store(v, reinterpret_cast<f32x4*>(p));
}

// ---- pre-pack kernels ----
__global__ void pack_k_kernel(const float* __restrict__ in, unsigned int* __restrict__ out, int n4){
  int i = blockIdx.x * 256 + threadIdx.x;
  if (i < n4){
    f32x4 x = ntload4(in + 4*(size_t)i);
    u32x4 p;
    p.x = packsplit(x.x); p.y = packsplit(x.y);
    p.z = packsplit(x.z); p.w = packsplit(x.w);
    reinterpret_cast<u32x4*>(out)[i] = p;
  }
}

__global__ void pack_vt_kernel(const float* __restrict__ v, unsigned int* __restrict__ vt){
  const int head = blockIdx.x >> 5;
  const int s0   = (blockIdx.x & 31) * 64;
  const float* vh = v + (size_t)head * S * DD;
  unsigned int* vth = vt + (size_t)head * DD * S;
  __shared__ unsigned int tile[64][65];
  const int tid = threadIdx.x;
  for (int i = tid; i < 64*64; i += 256){
    int s = i >> 6, d = i & 63;
    tile[d][s] = packsplit(__builtin_nontemporal_load(&vh[(size_t)(s0 + s) * DD + d]));
  }
  __syncthreads();
  for (int i = tid; i < 64*64; i += 256){
    int d = i >> 6, s = i & 63;
    vth[(size_t)d * S + s0 + s] = tile[d][s];
  }
}

// ---- fused attention ----
// NTST: weight stores nontemporal (A) vs plain cached (B) — within-round A/B.
template<bool PACKED, bool NTST>
__global__ __launch_bounds__(512, 2)
void attn_fused_kernel(const float* __restrict__ q, const float* __restrict__ k,
                       const float* __restrict__ v, const float* __restrict__ bias,
                       const float* __restrict__ gb,
                       const unsigned int* __restrict__ kp,
                       const unsigned int* __restrict__ vtp,
                       float* __restrict__ out, float* __restrict__ wout,
                       int head0)
{
  const int head = blockIdx.y + head0;
  const int q0   = blockIdx.x * 16;
  const int tid  = threadIdx.x;
  const int wid  = tid >> 6;
  const int lane = tid & 63;
  const int lr   = lane & 15;
  const int lg   = lane >> 4;

  const float* qh = q    + (size_t)head * S * DD;
  const float* kh = k    + (size_t)head * S * DD;
  const float* vh = v    + (size_t)head * S * DD;
  const float* bh = bias + (size_t)head * S * S;
  const float* gh = gb   + (size_t)head * S * S;
  const unsigned int* kph  = kp  + (size_t)head * S * DD;
  const unsigned int* vtph = vtp + (size_t)head * DD * S;
  float* oh = out  + (size_t)head * S * DD;
  float* wh = wout + (size_t)head * S * S;

  __shared__ unsigned int sW[NW][16][68];
  __shared__ float redm[NW][16];
  __shared__ float redl[NW][16];

  // ---- Q fragments (B operand: lane holds Q[q0+lr][32ks + lg*8+j]), pre-scaled
  bf16x8 qhi[2], qlo[2];
  {
    const float* qrow = qh + (size_t)(q0 + lr) * DD;
#pragma unroll
    for (int ks = 0; ks < 2; ++ks){
      float4 a = *reinterpret_cast<const float4*>(qrow + ks*32 + lg*8);
      float4 b = *reinterpret_cast<const float4*>(qrow + ks*32 + lg*8 + 4);
      float f[8] = {a.x,a.y,a.z,a.w,b.x,b.y,b.z,b.w};
#pragma unroll
      for (int j = 0; j < 8; ++j){
        short h, l2; split2(f[j] * 0.125f, h, l2);
        qhi[ks][j] = h; qlo[ks][j] = l2;
      }
    }
  }

  const int kw0 = wid * KSLICE;
  f32x4 acc[NT];
#pragma unroll
  for (int t = 0; t < NT; ++t) acc[t] = (f32x4){0.f,0.f,0.f,0.f};

  const float* brow = bh + (size_t)(q0 + lr) * S + kw0 + lg*4;
  const float* grow = gh + (size_t)(q0 + lr) * S + kw0 + lg*4;

  // ---- Phase 1: scores^T tile with 1-ahead bias/gb prefetch
  f32x4 b4 = ntload4(brow);
  f32x4 g4 = ntload4(grow);
#pragma unroll 2
  for (int t = 0; t < NT; ++t){
    f32x4 b4n = b4, g4n = g4;
    if (t < NT-1){
      b4n = ntload4(brow + 16*(t+1));
      g4n = ntload4(grow + 16*(t+1));
    }
    const int kbase = kw0 + 16*t;
    bf16x8 khi[2], klo[2];
    if constexpr (PACKED){
      const unsigned int* kr = kph + (size_t)(kbase + lr) * DD;
#pragma unroll
      for (int ks = 0; ks < 2; ++ks){
        uint4 p0 = *reinterpret_cast<const uint4*>(kr + ks*32 + lg*8);
        uint4 p1 = *reinterpret_cast<const uint4*>(kr + ks*32 + lg*8 + 4);
        unsigned int pw[8] = {p0.x,p0.y,p0.z,p0.w,p1.x,p1.y,p1.z,p1.w};
#pragma unroll
        for (int j = 0; j < 8; ++j){
          khi[ks][j] = (short)(pw[j] >> 16);
          klo[ks][j] = (short)(pw[j] & 0xFFFFu);
        }
      }
    } else {
      const float* krow = kh + (size_t)(kbase + lr) * DD;
#pragma unroll
      for (int ks = 0; ks < 2; ++ks){
        float4 a = *reinterpret_cast<const float4*>(krow + ks*32 + lg*8);
        float4 b = *reinterpret_cast<const float4*>(krow + ks*32 + lg*8 + 4);
        float f[8] = {a.x,a.y,a.z,a.w,b.x,b.y,b.z,b.w};
#pragma unroll
        for (int j = 0; j < 8; ++j){
          short h, l2; split2(f[j], h, l2);
          khi[ks][j] = h; klo[ks][j] = l2;
        }
      }
    }
#pragma unroll
    for (int ks = 0; ks < 2; ++ks){
      acc[t] = __builtin_amdgcn_mfma_f32_16x16x32_bf16(klo[ks], qhi[ks], acc[t], 0,0,0);
      acc[t] = __builtin_amdgcn_mfma_f32_16x16x32_bf16(khi[ks], qlo[ks], acc[t], 0,0,0);
      acc[t] = __builtin_amdgcn_mfma_f32_16x16x32_bf16(khi[ks], qhi[ks], acc[t], 0,0,0);
    }
#pragma unroll
    for (int r = 0; r < 4; ++r)
      acc[t][r] += b4[r] - 0.5f * g4[r] * g4[r];
    b4 = b4n; g4 = g4n;
  }

  // ---- Phase 2: softmax. Row q0+lr fully owned along (lg, r, t, wave).
  float mrow;
  {
    float mm = -3.4e38f;
#pragma unroll
    for (int t = 0; t < NT; ++t)
#pragma unroll
      for (int r = 0; r < 4; ++r) mm = fmaxf(mm, acc[t][r]);
    mm = fmaxf(mm, __shfl_xor(mm, 16, 64));
    mm = fmaxf(mm, __shfl_xor(mm, 32, 64));
    if (lane < 16) redm[wid][lane] = mm;
  }
  __syncthreads();
  {
    float mm = redm[0][lr];
#pragma unroll
    for (int w = 1; w < NW; ++w) mm = fmaxf(mm, redm[w][lr]);
    mrow = mm;
  }

  float inv;
  {
    float s = 0.f;
#pragma unroll
    for (int t = 0; t < NT; ++t)
#pragma unroll
      for (int r = 0; r < 4; ++r){
        float e = __expf(acc[t][r] - mrow);
        acc[t][r] = e;
        s += e;
      }
    s += __shfl_xor(s, 16, 64);
    s += __shfl_xor(s, 32, 64);
    if (lane < 16) redl[wid][lane] = s;
    __syncthreads();
    float tot = 0.f;
#pragma unroll
    for (int w = 0; w < NW; ++w) tot += redl[w][lr];
    inv = 1.0f / tot;
  }

  // ---- Phase 3+4: normalize+pack to LDS, full-line weight stores, PV
  f32x4 oacc[4];
#pragma unroll
  for (int n = 0; n < 4; ++n) oacc[n] = (f32x4){0.f,0.f,0.f,0.f};

  const int rg8 = lane >> 3;   // 0..7
  const int jj8 = lane & 7;    // 0..7

#pragma unroll 1
  for (int c = 0; c < 4; ++c){
#pragma unroll
    for (int tt = 0; tt < 4; ++tt){
      const int t = 4*c + tt;
      u32x4 pw;
#pragma unroll
      for (int r = 0; r < 4; ++r)
        pw[r] = packsplit(acc[t][r] * inv);
      *reinterpret_cast<u32x4*>(&sW[wid][lr][16*tt + lg*4]) = pw;
    }
    // wave-private weight write-out: 8 rows x 128B full-line segments per instr
#pragma unroll
    for (int p = 0; p < 2; ++p){
      const int row = p*8 + rg8;
#pragma unroll
      for (int h = 0; h < 2; ++h){
        u32x4 pk = *reinterpret_cast<const u32x4*>(&sW[wid][row][h*32 + jj8*4]);
        f32x4 wv;
#pragma unroll
        for (int e = 0; e < 4; ++e)
          wv[e] = __uint_as_float(pk[e] & 0xFFFF0000u) + __uint_as_float(pk[e] << 16);
        float* dst = wh + (size_t)(q0 + row) * S + kw0 + 64*c + h*32 + jj8*4;
        if constexpr (NTST) ntstore4(dst, wv);
        else *reinterpret_cast<f32x4*>(dst) = wv;
      }
    }
    const int kc = kw0 + 64*c;
#pragma unroll
    for (int ks = 0; ks < 2; ++ks){
      uint4 pa0 = *reinterpret_cast<const uint4*>(&sW[wid][lr][32*ks + lg*8]);
      uint4 pa1 = *reinterpret_cast<const uint4*>(&sW[wid][lr][32*ks + lg*8 + 4]);
      unsigned int pa[8] = {pa0.x,pa0.y,pa0.z,pa0.w,pa1.x,pa1.y,pa1.z,pa1.w};
      bf16x8 ahi, alo;
#pragma unroll
      for (int j = 0; j < 8; ++j){
        ahi[j] = (short)(pa[j] >> 16);
        alo[j] = (short)(pa[j] & 0xFFFFu);
      }
#pragma unroll
      for (int n = 0; n < 4; ++n){
        bf16x8 bhi, blo;
        if constexpr (PACKED){
          const unsigned int* vrow = vtph + (size_t)(16*n + lr) * S + kc + 32*ks + lg*8;
          uint4 p0 = *reinterpret_cast<const uint4*>(vrow);
          uint4 p1 = *reinterpret_cast<const uint4*>(vrow + 4);
          unsigned int pw[8] = {p0.x,p0.y,p0.z,p0.w,p1.x,p1.y,p1.z,p1.w};
#pragma unroll
          for (int j = 0; j < 8; ++j){
            bhi[j] = (short)(pw[j] >> 16);
            blo[j] = (short)(pw[j] & 0xFFFFu);
          }
        } else {
#pragma unroll
          for (int j = 0; j < 8; ++j){
            float x = vh[(size_t)(kc + 32*ks + lg*8 + j) * DD + 16*n + lr];
            short h, l2; split2(x, h, l2);
            bhi[j] = h; blo[j] = l2;
          }
        }
        oacc[n] = __builtin_amdgcn_mfma_f32_16x16x32_bf16(alo, bhi, oacc[n], 0,0,0);
        oacc[n] = __builtin_amdgcn_mfma_f32_16x16x32_bf16(ahi, blo, oacc[n], 0,0,0);
        oacc[n] = __builtin_amdgcn_mfma_f32_16x16x32_bf16(ahi, bhi, oacc[n], 0,0,0);
      }
    }
  }

  // ---- Phase 5: cross-wave reduction of out partials (alias sW)
  float (*sO)[16][68] = reinterpret_cast<float(*)[16][68]>(sW);
  __syncthreads();
#pragma unroll
  for (int n = 0; n < 4; ++n)
#pragma unroll
    for (int r = 0; r < 4; ++r)
      sO[wid][lg*4 + r][16*n + lr] = oacc[n][r];
  __syncthreads();
#pragma unroll
  for (int i = tid; i < 16*64; i += 512){
    int row = i >> 6, d = i & 63;
    float s = 0.f;
#pragma unroll
    for (int w = 0; w < NW; ++w) s += sO[w][row][d];
    __builtin_nontemporal_store(s, &oh[(size_t)(q0 + row) * DD + d]);
  }
}

extern "C" void kernel_launch(void* const* d_in, const int* in_sizes, int n_in,
                              void* d_out, int out_size, void* d_ws, size_t ws_size,
                              hipStream_t stream) {
  const float* q    = (const float*)d_in[0];
  const float* k    = (const float*)d_in[1];
  const float* v    = (const float*)d_in[2];
  const float* bias = (const float*)d_in[3];
  const float* gb   = (const float*)d_in[4];
  float* out  = (float*)d_out;
  float* wout = (float*)d_out + (size_t)NH * S * DD;

  const size_t nelem = (size_t)NH * S * DD;       // 4.19M
  const size_t need  = 2 * nelem * sizeof(unsigned int);

  dim3 grid(S / 16, NH / 2);
  dim3 block(512);

  if (ws_size >= need){
    unsigned int* kp  = (unsigned int*)d_ws;
    unsigned int* vtp = kp + nelem;
    int n4 = (int)(nelem / 4);
    pack_k_kernel<<<(n4 + 255) / 256, 256, 0, stream>>>(k, kp, n4);
    pack_vt_kernel<<<NH * 32, 256, 0, stream>>>(v, vtp);
    // A: heads 0..15 nontemporal weight stores
    attn_fused_kernel<true, true ><<<grid, block, 0, stream>>>(q, k, v, bias, gb, kp, vtp, out, wout, 0);
    // B: heads 16..31 plain cached weight stores
    attn_fused_kernel<true, false><<<grid, block, 0, stream>>>(q, k, v, bias, gb, kp, vtp, out, wout, NH/2);
  } else {
    attn_fused_kernel<false, true ><<<grid, block, 0, stream>>>(q, k, v, bias, gb, nullptr, nullptr, out, wout, 0);
    attn_fused_kernel<false, false><<<grid, block, 0, stream>>>(q, k, v, bias, gb, nullptr, nullptr, out, wout, NH/2);
  }
}

// Round 6
// 1203.779 us; speedup vs baseline: 1.0506x; 1.0284x over previous
//
#include <hip/hip_runtime.h>

#define S 2048
#define DD 64
#define NH 32           // B*H
#define NW 8            // waves per block
#define KSLICE 256      // k columns per wave
#define NT 16           // 16-wide k tiles per wave

typedef float f32x4 __attribute__((ext_vector_type(4)));
typedef unsigned int u32x4 __attribute__((ext_vector_type(4)));
typedef short bf16x8 __attribute__((ext_vector_type(8)));

__device__ inline unsigned int packsplit(float x){
  unsigned int u = __float_as_uint(x);
  unsigned int h = u >> 16;
  float rem = x - __uint_as_float(h << 16);
  unsigned int l = __float_as_uint(rem) >> 16;
  return (h << 16) | l;
}
__device__ inline void split2(float x, short &hi, short &lo){
  unsigned int p = packsplit(x);
  hi = (short)(p >> 16); lo = (short)(p & 0xFFFFu);
}
__device__ inline f32x4 ntload4(const float* p){
  return __builtin_nontemporal_load(reinterpret_cast<const f32x4*>(p));
}
__device__ inline void ntstore4(float* p, f32x4 v){
  __builtin_nontemporal_store(v, reinterpret_cast<f32x4*>(p));
}

// ---- pre-pack kernels ----
__global__ void pack_k_kernel(const float* __restrict__ in, unsigned int* __restrict__ out, int n4){
  int i = blockIdx.x * 256 + threadIdx.x;
  if (i < n4){
    f32x4 x = ntload4(in + 4*(size_t)i);
    u32x4 p;
    p.x = packsplit(x.x); p.y = packsplit(x.y);
    p.z = packsplit(x.z); p.w = packsplit(x.w);
    reinterpret_cast<u32x4*>(out)[i] = p;
  }
}

__global__ void pack_vt_kernel(const float* __restrict__ v, unsigned int* __restrict__ vt){
  const int head = blockIdx.x >> 5;
  const int s0   = (blockIdx.x & 31) * 64;
  const float* vh = v + (size_t)head * S * DD;
  unsigned int* vth = vt + (size_t)head * DD * S;
  __shared__ unsigned int tile[64][65];
  const int tid = threadIdx.x;
  for (int i = tid; i < 64*64; i += 256){
    int s = i >> 6, d = i & 63;
    tile[d][s] = packsplit(__builtin_nontemporal_load(&vh[(size_t)(s0 + s) * DD + d]));
  }
  __syncthreads();
  for (int i = tid; i < 64*64; i += 256){
    int d = i >> 6, s = i & 63;
    vth[(size_t)d * S + s0 + s] = tile[d][s];
  }
}

// ---- fused attention ----
template<bool PACKED>
__global__ __launch_bounds__(512, 4)   // pin regs <=128/wave: 2 blocks/CU always
void attn_fused_kernel(const float* __restrict__ q, const float* __restrict__ k,
                       const float* __restrict__ v, const float* __restrict__ bias,
                       const float* __restrict__ gb,
                       const unsigned int* __restrict__ kp,
                       const unsigned int* __restrict__ vtp,
                       float* __restrict__ out, float* __restrict__ wout)
{
  const int head = blockIdx.y;
  const int q0   = blockIdx.x * 16;
  const int tid  = threadIdx.x;
  const int wid  = tid >> 6;
  const int lane = tid & 63;
  const int lr   = lane & 15;
  const int lg   = lane >> 4;

  const float* qh = q    + (size_t)head * S * DD;
  const float* kh = k    + (size_t)head * S * DD;
  const float* vh = v    + (size_t)head * S * DD;
  const float* bh = bias + (size_t)head * S * S;
  const float* gh = gb   + (size_t)head * S * S;
  const unsigned int* kph  = kp  + (size_t)head * S * DD;
  const unsigned int* vtph = vtp + (size_t)head * DD * S;
  float* oh = out  + (size_t)head * S * DD;
  float* wh = wout + (size_t)head * S * S;

  __shared__ unsigned int sW[NW][16][68];
  __shared__ float redm[NW][16];
  __shared__ float redl[NW][16];

  const int kw0 = wid * KSLICE;
  f32x4 acc[NT];

  // ---- Phase 0: acc[t] = bias - 0.5*g^2 — pure HBM streaming loop, no MFMA
  //      interference; compiler pipelines loads to the reg cap. MFMA later
  //      accumulates QK^T on top (C operand is free).
  {
    const float* brow = bh + (size_t)(q0 + lr) * S + kw0 + lg*4;
    const float* grow = gh + (size_t)(q0 + lr) * S + kw0 + lg*4;
#pragma unroll 4
    for (int t = 0; t < NT; ++t){
      f32x4 b4 = *reinterpret_cast<const f32x4*>(brow + 16*t);
      f32x4 g4 = *reinterpret_cast<const f32x4*>(grow + 16*t);
#pragma unroll
      for (int r = 0; r < 4; ++r)
        acc[t][r] = b4[r] - 0.5f * g4[r] * g4[r];
    }
  }

  // ---- Q fragments (B operand: lane holds Q[q0+lr][32ks + lg*8+j]), pre-scaled
  bf16x8 qhi[2], qlo[2];
  {
    const float* qrow = qh + (size_t)(q0 + lr) * DD;
#pragma unroll
    for (int ks = 0; ks < 2; ++ks){
      float4 a = *reinterpret_cast<const float4*>(qrow + ks*32 + lg*8);
      float4 b = *reinterpret_cast<const float4*>(qrow + ks*32 + lg*8 + 4);
      float f[8] = {a.x,a.y,a.z,a.w,b.x,b.y,b.z,b.w};
#pragma unroll
      for (int j = 0; j < 8; ++j){
        short h, l2; split2(f[j] * 0.125f, h, l2);
        qhi[ks][j] = h; qlo[ks][j] = l2;
      }
    }
  }

  // ---- Phase 1: QK^T on top of bias-initialized acc (K is L2-resident)
#pragma unroll 2
  for (int t = 0; t < NT; ++t){
    const int kbase = kw0 + 16*t;
    bf16x8 khi[2], klo[2];
    if constexpr (PACKED){
      const unsigned int* kr = kph + (size_t)(kbase + lr) * DD;
#pragma unroll
      for (int ks = 0; ks < 2; ++ks){
        uint4 p0 = *reinterpret_cast<const uint4*>(kr + ks*32 + lg*8);
        uint4 p1 = *reinterpret_cast<const uint4*>(kr + ks*32 + lg*8 + 4);
        unsigned int pw[8] = {p0.x,p0.y,p0.z,p0.w,p1.x,p1.y,p1.z,p1.w};
#pragma unroll
        for (int j = 0; j < 8; ++j){
          khi[ks][j] = (short)(pw[j] >> 16);
          klo[ks][j] = (short)(pw[j] & 0xFFFFu);
        }
      }
    } else {
      const float* krow = kh + (size_t)(kbase + lr) * DD;
#pragma unroll
      for (int ks = 0; ks < 2; ++ks){
        float4 a = *reinterpret_cast<const float4*>(krow + ks*32 + lg*8);
        float4 b = *reinterpret_cast<const float4*>(krow + ks*32 + lg*8 + 4);
        float f[8] = {a.x,a.y,a.z,a.w,b.x,b.y,b.z,b.w};
#pragma unroll
        for (int j = 0; j < 8; ++j){
          short h, l2; split2(f[j], h, l2);
          khi[ks][j] = h; klo[ks][j] = l2;
        }
      }
    }
#pragma unroll
    for (int ks = 0; ks < 2; ++ks){
      acc[t] = __builtin_amdgcn_mfma_f32_16x16x32_bf16(klo[ks], qhi[ks], acc[t], 0,0,0);
      acc[t] = __builtin_amdgcn_mfma_f32_16x16x32_bf16(khi[ks], qlo[ks], acc[t], 0,0,0);
      acc[t] = __builtin_amdgcn_mfma_f32_16x16x32_bf16(khi[ks], qhi[ks], acc[t], 0,0,0);
    }
  }

  // ---- Phase 2: softmax. Row q0+lr fully owned along (lg, r, t, wave).
  float mrow;
  {
    float mm = -3.4e38f;
#pragma unroll
    for (int t = 0; t < NT; ++t)
#pragma unroll
      for (int r = 0; r < 4; ++r) mm = fmaxf(mm, acc[t][r]);
    mm = fmaxf(mm, __shfl_xor(mm, 16, 64));
    mm = fmaxf(mm, __shfl_xor(mm, 32, 64));
    if (lane < 16) redm[wid][lane] = mm;
  }
  __syncthreads();
  {
    float mm = redm[0][lr];
#pragma unroll
    for (int w = 1; w < NW; ++w) mm = fmaxf(mm, redm[w][lr]);
    mrow = mm;
  }

  float inv;
  {
    float s = 0.f;
#pragma unroll
    for (int t = 0; t < NT; ++t)
#pragma unroll
      for (int r = 0; r < 4; ++r){
        float e = __expf(acc[t][r] - mrow);
        acc[t][r] = e;
        s += e;
      }
    s += __shfl_xor(s, 16, 64);
    s += __shfl_xor(s, 32, 64);
    if (lane < 16) redl[wid][lane] = s;
    __syncthreads();
    float tot = 0.f;
#pragma unroll
    for (int w = 0; w < NW; ++w) tot += redl[w][lr];
    inv = 1.0f / tot;
  }

  // ---- Phase 3+4: normalize, direct frag-layout weight stores, pack to LDS, PV
  f32x4 oacc[4];
#pragma unroll
  for (int n = 0; n < 4; ++n) oacc[n] = (f32x4){0.f,0.f,0.f,0.f};

  float* wrow = wh + (size_t)(q0 + lr) * S + kw0 + lg*4;

#pragma unroll 1
  for (int c = 0; c < 4; ++c){
#pragma unroll
    for (int tt = 0; tt < 4; ++tt){
      const int t = 4*c + tt;
      f32x4 w4; u32x4 pw;
#pragma unroll
      for (int r = 0; r < 4; ++r){
        float w = acc[t][r] * inv;
        w4[r] = w;
        pw[r] = packsplit(w);
      }
      ntstore4(wrow + 16*t, w4);
      *reinterpret_cast<u32x4*>(&sW[wid][lr][16*tt + lg*4]) = pw;
    }
    const int kc = kw0 + 64*c;
#pragma unroll
    for (int ks = 0; ks < 2; ++ks){
      uint4 pa0 = *reinterpret_cast<const uint4*>(&sW[wid][lr][32*ks + lg*8]);
      uint4 pa1 = *reinterpret_cast<const uint4*>(&sW[wid][lr][32*ks + lg*8 + 4]);
      unsigned int pa[8] = {pa0.x,pa0.y,pa0.z,pa0.w,pa1.x,pa1.y,pa1.z,pa1.w};
      bf16x8 ahi, alo;
#pragma unroll
      for (int j = 0; j < 8; ++j){
        ahi[j] = (short)(pa[j] >> 16);
        alo[j] = (short)(pa[j] & 0xFFFFu);
      }
#pragma unroll
      for (int n = 0; n < 4; ++n){
        bf16x8 bhi, blo;
        if constexpr (PACKED){
          const unsigned int* vrow = vtph + (size_t)(16*n + lr) * S + kc + 32*ks + lg*8;
          uint4 p0 = *reinterpret_cast<const uint4*>(vrow);
          uint4 p1 = *reinterpret_cast<const uint4*>(vrow + 4);
          unsigned int pw[8] = {p0.x,p0.y,p0.z,p0.w,p1.x,p1.y,p1.z,p1.w};
#pragma unroll
          for (int j = 0; j < 8; ++j){
            bhi[j] = (short)(pw[j] >> 16);
            blo[j] = (short)(pw[j] & 0xFFFFu);
          }
        } else {
#pragma unroll
          for (int j = 0; j < 8; ++j){
            float x = vh[(size_t)(kc + 32*ks + lg*8 + j) * DD + 16*n + lr];
            short h, l2; split2(x, h, l2);
            bhi[j] = h; blo[j] = l2;
          }
        }
        oacc[n] = __builtin_amdgcn_mfma_f32_16x16x32_bf16(alo, bhi, oacc[n], 0,0,0);
        oacc[n] = __builtin_amdgcn_mfma_f32_16x16x32_bf16(ahi, blo, oacc[n], 0,0,0);
        oacc[n] = __builtin_amdgcn_mfma_f32_16x16x32_bf16(ahi, bhi, oacc[n], 0,0,0);
      }
    }
  }

  // ---- Phase 5: cross-wave reduction of out partials (alias sW)
  float (*sO)[16][68] = reinterpret_cast<float(*)[16][68]>(sW);
  __syncthreads();
#pragma unroll
  for (int n = 0; n < 4; ++n)
#pragma unroll
    for (int r = 0; r < 4; ++r)
      sO[wid][lg*4 + r][16*n + lr] = oacc[n][r];
  __syncthreads();
#pragma unroll
  for (int i = tid; i < 16*64; i += 512){
    int row = i >> 6, d = i & 63;
    float s = 0.f;
#pragma unroll
    for (int w = 0; w < NW; ++w) s += sO[w][row][d];
    __builtin_nontemporal_store(s, &oh[(size_t)(q0 + row) * DD + d]);
  }
}

extern "C" void kernel_launch(void* const* d_in, const int* in_sizes, int n_in,
                              void* d_out, int out_size, void* d_ws, size_t ws_size,
                              hipStream_t stream) {
  const float* q    = (const float*)d_in[0];
  const float* k    = (const float*)d_in[1];
  const float* v    = (const float*)d_in[2];
  const float* bias = (const float*)d_in[3];
  const float* gb   = (const float*)d_in[4];
  float* out  = (float*)d_out;
  float* wout = (float*)d_out + (size_t)NH * S * DD;

  const size_t nelem = (size_t)NH * S * DD;       // 4.19M
  const size_t need  = 2 * nelem * sizeof(unsigned int);

  dim3 grid(S / 16, NH);
  dim3 block(512);

  if (ws_size >= need){
    unsigned int* kp  = (unsigned int*)d_ws;
    unsigned int* vtp = kp + nelem;
    int n4 = (int)(nelem / 4);
    pack_k_kernel<<<(n4 + 255) / 256, 256, 0, stream>>>(k, kp, n4);
    pack_vt_kernel<<<NH * 32, 256, 0, stream>>>(v, vtp);
    attn_fused_kernel<true ><<<grid, block, 0, stream>>>(q, k, v, bias, gb, kp, vtp, out, wout);
  } else {
    attn_fused_kernel<false><<<grid, block, 0, stream>>>(q, k, v, bias, gb, nullptr, nullptr, out, wout);
  }
}